// Round 9
// baseline (206.384 us; speedup 1.0000x reference)
//
#include <hip/hip_runtime.h>
#include <math.h>

#define BETA  0.125f    // 1/sqrt(64)
#define SHIFT 30.0f     // fixed softmax shift; logits bounded in [0.125, 68.5]
#define EPSF  1e-7f

typedef __attribute__((ext_vector_type(8))) short short8;
typedef __attribute__((ext_vector_type(4))) short short4v;
typedef __attribute__((ext_vector_type(4))) float f32x4;

__device__ __forceinline__ unsigned short bf16_rne(float x) {
  unsigned int u = __float_as_uint(x);
  return (unsigned short)((u + 0x7fffu + ((u >> 16) & 1u)) >> 16);
}
__device__ __forceinline__ float bf16_tof(unsigned short h) {
  return __uint_as_float(((unsigned int)h) << 16);
}
__device__ __forceinline__ void split2(float x, unsigned short& h, unsigned short& l) {
  unsigned int u = __float_as_uint(x);
  unsigned int hr = (u + 0x7fffu + ((u >> 16) & 1u)) & 0xffff0000u;  // RNE hi
  h = (unsigned short)(hr >> 16);
  l = bf16_rne(x - __uint_as_float(hr));
}

#define ZERO_F4 68608   // (262144 + 12288) floats / 4: Tacc + scalar accums

// ---------------------------------------------------------------------------
// Merged projection. Blocks 0..127: V (double proj, heavy — dispatched first
// for load balance); 128..255: K; 256..319: Q. Also zeroes the attention
// accumulator region (stream-ordered before attn).
// ---------------------------------------------------------------------------
__global__ __launch_bounds__(256) void proj_kernel(
    const float* __restrict__ Xq, const float* __restrict__ Xk,
    const float* __restrict__ Xv,
    const float* __restrict__ Wq, const float* __restrict__ bq,
    const float* __restrict__ Wk, const float* __restrict__ bk,
    const float* __restrict__ Wv, const float* __restrict__ bv,
    float* __restrict__ Q0, float* __restrict__ K0, float* __restrict__ V0,
    unsigned short* __restrict__ Qh, unsigned short* __restrict__ Ql,
    unsigned short* __restrict__ Kh, unsigned short* __restrict__ Kl,
    unsigned short* __restrict__ Vh, unsigned short* __restrict__ Vl,
    unsigned short* __restrict__ Vth, unsigned short* __restrict__ Vtl,
    float* __restrict__ zeroRegion)
{
  __shared__ float Xs[64 * 64];
  __shared__ float Ws[64 * 64];
  __shared__ unsigned int Tr[64 * 65];   // dedicated transpose buffer (V only)

  const int bid = blockIdx.x;
  const int tid = threadIdx.x;

  // zero the attention accumulators (grid-stride, one float4 per thread)
  {
    int idx = bid * 256 + tid;
    if (idx < ZERO_F4)
      *(float4*)&zeroRegion[idx * 4] = make_float4(0.f, 0.f, 0.f, 0.f);
  }

  const float *X, *W, *bias;
  float* y0;
  unsigned short *yh, *yl;
  bool dbl;
  int rowBase;
  if (bid < 128)      { X = Xv; W = Wk; bias = bk; y0 = V0; yh = Vh; yl = Vl; rowBase = bid << 6;         dbl = true;  }
  else if (bid < 256) { X = Xk; W = Wk; bias = bk; y0 = K0; yh = Kh; yl = Kl; rowBase = (bid - 128) << 6; dbl = false; }
  else                { X = Xq; W = Wq; bias = bq; y0 = Q0; yh = Qh; yl = Ql; rowBase = (bid - 256) << 6; dbl = false; }

  const int ty = tid >> 4, tx = tid & 15;
  const int ty4 = ty << 2, tx4 = tx << 2;

  float acc[4][4];
#pragma unroll
  for (int j = 0; j < 4; ++j) {
    float bj = bias[tx4 + j];
#pragma unroll
    for (int i = 0; i < 4; ++i) acc[i][j] = bj;
  }

  for (int kc = 0; kc < 4; ++kc) {
#pragma unroll
    for (int q = 0; q < 4; ++q) {
      int f = tid + (q << 8);
      int r = f >> 4, g = f & 15;
      int sw = (r << 6) + ((g ^ (r >> 2)) << 2);
      *(float4*)&Xs[sw] = *(const float4*)&X[(rowBase + r) * 256 + (kc << 6) + (g << 2)];
      *(float4*)&Ws[sw] = *(const float4*)&W[r * 256 + (kc << 6) + (g << 2)];
    }
    __syncthreads();
#pragma unroll 4
    for (int kk = 0; kk < 64; kk += 4) {
      const int gk = kk >> 2;
      float4 xa[4], wb[4];
#pragma unroll
      for (int i = 0; i < 4; ++i)
        xa[i] = *(const float4*)&Xs[((ty4 + i) << 6) + ((gk ^ ty) << 2)];
#pragma unroll
      for (int j = 0; j < 4; ++j)
        wb[j] = *(const float4*)&Ws[((tx4 + j) << 6) + ((gk ^ tx) << 2)];
#pragma unroll
      for (int i = 0; i < 4; ++i)
#pragma unroll
        for (int j = 0; j < 4; ++j)
          acc[i][j] += xa[i].x * wb[j].x + xa[i].y * wb[j].y +
                       xa[i].z * wb[j].z + xa[i].w * wb[j].w;
    }
    __syncthreads();
  }

  if (dbl) {
#pragma unroll
    for (int i = 0; i < 4; ++i) {
      float4 v = make_float4(acc[i][0], acc[i][1], acc[i][2], acc[i][3]);
      *(float4*)&Xs[((ty4 + i) << 6) + ((tx ^ ty) << 2)] = v;
    }
#pragma unroll
    for (int q = 0; q < 4; ++q) {
      int f = tid + (q << 8);
      int r = f >> 4, g = f & 15;
      int sw = (r << 6) + ((g ^ (r >> 2)) << 2);
      *(float4*)&Ws[sw] = *(const float4*)&Wv[(r << 6) + (g << 2)];
    }
#pragma unroll
    for (int j = 0; j < 4; ++j) {
      float bj = bv[tx4 + j];
#pragma unroll
      for (int i = 0; i < 4; ++i) acc[i][j] = bj;
    }
    __syncthreads();
#pragma unroll 4
    for (int kk = 0; kk < 64; kk += 4) {
      const int gk = kk >> 2;
      float4 xa[4], wb[4];
#pragma unroll
      for (int i = 0; i < 4; ++i)
        xa[i] = *(const float4*)&Xs[((ty4 + i) << 6) + ((gk ^ ty) << 2)];
#pragma unroll
      for (int j = 0; j < 4; ++j)
        wb[j] = *(const float4*)&Ws[((tx4 + j) << 6) + ((gk ^ tx) << 2)];
#pragma unroll
      for (int i = 0; i < 4; ++i)
#pragma unroll
        for (int j = 0; j < 4; ++j)
          acc[i][j] += xa[i].x * wb[j].x + xa[i].y * wb[j].y +
                       xa[i].z * wb[j].z + xa[i].w * wb[j].w;
    }
  }

  // expmap0 epilogue in registers + shuffles
  float n2p[4];
#pragma unroll
  for (int i = 0; i < 4; ++i)
    n2p[i] = acc[i][0] * acc[i][0] + acc[i][1] * acc[i][1] +
             acc[i][2] * acc[i][2] + acc[i][3] * acc[i][3];
#pragma unroll
  for (int i = 0; i < 4; ++i) {
    n2p[i] += __shfl_xor(n2p[i], 1);
    n2p[i] += __shfl_xor(n2p[i], 2);
    n2p[i] += __shfl_xor(n2p[i], 4);
    n2p[i] += __shfl_xor(n2p[i], 8);
  }
  unsigned short hv[4][4], lv[4][4];
#pragma unroll
  for (int i = 0; i < 4; ++i) {
    float n = sqrtf(n2p[i]);
    float factor = fminf(3.5f / (n + EPSF), 1.0f);
    float xn = fmaxf(n * factor, EPSF);
    float et = __expf(xn);
    float rt = __builtin_amdgcn_rcpf(et);
    float ch = 0.5f * (et + rt);
    float sh = 0.5f * (et - rt);
    float scale = sh * factor * __builtin_amdgcn_rcpf(xn);
    int row = rowBase + ty4 + i;
    if (tx == 0) y0[row] = ch;
#pragma unroll
    for (int j = 0; j < 4; ++j) split2(acc[i][j] * scale, hv[i][j], lv[i][j]);
    unsigned int* ph = (unsigned int*)(yh + row * 64 + tx4);
    ph[0] = (unsigned int)hv[i][0] | ((unsigned int)hv[i][1] << 16);
    ph[1] = (unsigned int)hv[i][2] | ((unsigned int)hv[i][3] << 16);
    unsigned int* pl = (unsigned int*)(yl + row * 64 + tx4);
    pl[0] = (unsigned int)lv[i][0] | ((unsigned int)lv[i][1] << 16);
    pl[1] = (unsigned int)lv[i][2] | ((unsigned int)lv[i][3] << 16);
  }

  if (dbl) {
    // transposed copies via dedicated LDS buffer; two passes (hi, lo)
#pragma unroll
    for (int i = 0; i < 4; ++i)
#pragma unroll
      for (int j = 0; j < 4; ++j)
        Tr[(ty4 + i) * 65 + tx4 + j] = (unsigned int)hv[i][j];
    __syncthreads();
#pragma unroll
    for (int q = 0; q < 2; ++q) {
      int f = tid + (q << 8);
      int d = f >> 3;                // 0..63
      int seg = (f & 7) << 3;        // 0,8,..,56
      unsigned int o[4];
#pragma unroll
      for (int k = 0; k < 4; ++k)
        o[k] = Tr[(seg + 2 * k) * 65 + d] | (Tr[(seg + 2 * k + 1) * 65 + d] << 16);
      *(uint4*)&Vth[d * 8192 + rowBase + seg] = make_uint4(o[0], o[1], o[2], o[3]);
    }
    __syncthreads();
#pragma unroll
    for (int i = 0; i < 4; ++i)
#pragma unroll
      for (int j = 0; j < 4; ++j)
        Tr[(ty4 + i) * 65 + tx4 + j] = (unsigned int)lv[i][j];
    __syncthreads();
#pragma unroll
    for (int q = 0; q < 2; ++q) {
      int f = tid + (q << 8);
      int d = f >> 3;
      int seg = (f & 7) << 3;
      unsigned int o[4];
#pragma unroll
      for (int k = 0; k < 4; ++k)
        o[k] = Tr[(seg + 2 * k) * 65 + d] | (Tr[(seg + 2 * k + 1) * 65 + d] << 16);
      *(uint4*)&Vtl[d * 8192 + rowBase + seg] = make_uint4(o[0], o[1], o[2], o[3]);
    }
  }
}

// ---------------------------------------------------------------------------
// MFMA attention core, si=1 split: one wave = 16 s-rows x one m-slice
// (4096 waves = 1024 WGs -> 4 waves/SIMD). Slice partials accumulate via
// HW f32 atomics into Tacc (zeroed by proj). Zero __syncthreads.
// ---------------------------------------------------------------------------
__global__ __launch_bounds__(256, 4) void attn_kernel(
    const float* __restrict__ Q0g, const unsigned short* __restrict__ Qh,
    const unsigned short* __restrict__ Ql,
    const float* __restrict__ K0g, const unsigned short* __restrict__ Kh,
    const unsigned short* __restrict__ Kl,
    const float* __restrict__ V0g, const unsigned short* __restrict__ Vh,
    const unsigned short* __restrict__ Vl,
    const unsigned short* __restrict__ Vth, const unsigned short* __restrict__ Vtl,
    float* __restrict__ Tacc, float* __restrict__ T0acc,
    float* __restrict__ Lacc, float* __restrict__ WCacc)
{
  __shared__ unsigned short Wlds[4 * 16 * 68];

  const int tid = threadIdx.x;
  const int wave = tid >> 6, lane = tid & 63;
  const int lm = lane & 15;
  const int lg = lane >> 4;
  const int Wid = blockIdx.x * 4 + wave;       // 0..4095
  const int slice = Wid & 15;                  // SL = 16
  const int sTb = Wid >> 4;                    // 0..255
  const int sT = sTb & 127;
  const int b = sTb >> 7;
  const int sBase = b * 2048 + sT * 16;

  unsigned short* wbase = Wlds + wave * (16 * 68);

  // loop-invariant Q fragments [kstep][hi/lo]
  short8 qf[2][2];
#pragma unroll
  for (int ks = 0; ks < 2; ++ks) {
    int idx = (sBase + lm) * 64 + ks * 32 + lg * 8;
    qf[ks][0] = *(const short8*)(Qh + idx);
    qf[ks][1] = *(const short8*)(Ql + idx);
  }
  float q0r[4];
#pragma unroll
  for (int r = 0; r < 4; ++r) q0r[r] = Q0g[sBase + lg * 4 + r];

  f32x4 accT[4];
  float Lp[4], WCp[4], T0p[4];
#pragma unroll
  for (int r = 0; r < 4; ++r) { Lp[r] = 0.f; WCp[r] = 0.f; T0p[r] = 0.f; }
#pragma unroll
  for (int dj = 0; dj < 4; ++dj) accT[dj] = f32x4{0.f, 0.f, 0.f, 0.f};

  const int mSliceBase = b * 4096 + slice * 256;   // nChunk = 4
  for (int mc = 0; mc < 4; ++mc) {
    const int mCh = mSliceBase + (mc << 6);
    float k0r[4], v0r[4];
#pragma unroll
    for (int mj = 0; mj < 4; ++mj) {
      k0r[mj] = K0g[mCh + mj * 16 + lm];
      v0r[mj] = V0g[mCh + mj * 16 + lm];
    }

    // Phase A: sims = Qr.Kr, ipv = Qr.Vr via split-bf16 MFMA
    f32x4 sims[4], ipv[4];
#pragma unroll
    for (int mj = 0; mj < 4; ++mj) {
      sims[mj] = f32x4{0.f, 0.f, 0.f, 0.f};
      ipv[mj]  = f32x4{0.f, 0.f, 0.f, 0.f};
    }
#pragma unroll
    for (int mj = 0; mj < 4; ++mj) {
#pragma unroll
      for (int ks = 0; ks < 2; ++ks) {
        int bidx = (mCh + mj * 16 + lm) * 64 + ks * 32 + lg * 8;
        short8 kh = *(const short8*)(Kh + bidx);
        short8 kl = *(const short8*)(Kl + bidx);
        short8 vh = *(const short8*)(Vh + bidx);
        short8 vl = *(const short8*)(Vl + bidx);
        sims[mj] = __builtin_amdgcn_mfma_f32_16x16x32_bf16(qf[ks][0], kh, sims[mj], 0, 0, 0);
        sims[mj] = __builtin_amdgcn_mfma_f32_16x16x32_bf16(qf[ks][0], kl, sims[mj], 0, 0, 0);
        sims[mj] = __builtin_amdgcn_mfma_f32_16x16x32_bf16(qf[ks][1], kh, sims[mj], 0, 0, 0);
        ipv[mj]  = __builtin_amdgcn_mfma_f32_16x16x32_bf16(qf[ks][0], vh, ipv[mj], 0, 0, 0);
        ipv[mj]  = __builtin_amdgcn_mfma_f32_16x16x32_bf16(qf[ks][0], vl, ipv[mj], 0, 0, 0);
        ipv[mj]  = __builtin_amdgcn_mfma_f32_16x16x32_bf16(qf[ks][1], vh, ipv[mj], 0, 0, 0);
      }
    }

    // elementwise: w = e * acosh(-c) * rsq(c^2-1)
#pragma unroll
    for (int mj = 0; mj < 4; ++mj)
#pragma unroll
      for (int r = 0; r < 4; ++r) {
        float c  = ipv[mj][r]  - q0r[r] * v0r[mj];
        float sm = sims[mj][r] - q0r[r] * k0r[mj];
        float x = -c;
        float s2 = fmaxf(fmaf(x, x, -1.0f), EPSF);
        float rs = __builtin_amdgcn_rsqf(s2);
        float dist = __logf(fmaf(s2, rs, x));
        float e = __expf(fmaf(-BETA, sm, -SHIFT));
        float w = e * dist * rs;
        unsigned short wu = bf16_rne(w);
        float wb = bf16_tof(wu);
        Lp[r]  += e;
        WCp[r] += wb * c;
        T0p[r] += wb * v0r[mj];
        wbase[(lg * 4 + r) * 68 + mj * 16 + lm] = wu;
      }

    // Phase B: T[s][d] += W[s][m] * V[m][d]
#pragma unroll
    for (int ks = 0; ks < 2; ++ks) {
      const unsigned short* p = wbase + lm * 68 + ks * 32 + lg * 8;
      short4v a0 = *(const short4v*)p;
      short4v a1 = *(const short4v*)(p + 4);
      short8 wa = __builtin_shufflevector(a0, a1, 0, 1, 2, 3, 4, 5, 6, 7);
#pragma unroll
      for (int dj = 0; dj < 4; ++dj) {
        int vidx = (dj * 16 + lm) * 8192 + mCh + ks * 32 + lg * 8;
        short8 th = *(const short8*)(Vth + vidx);
        short8 tl = *(const short8*)(Vtl + vidx);
        accT[dj] = __builtin_amdgcn_mfma_f32_16x16x32_bf16(wa, th, accT[dj], 0, 0, 0);
        accT[dj] = __builtin_amdgcn_mfma_f32_16x16x32_bf16(wa, tl, accT[dj], 0, 0, 0);
      }
    }
  }

  // reduce row scalars across the 16 col-lanes
#pragma unroll
  for (int r = 0; r < 4; ++r)
#pragma unroll
    for (int off = 1; off < 16; off <<= 1) {
      Lp[r]  += __shfl_xor(Lp[r], off);
      WCp[r] += __shfl_xor(WCp[r], off);
      T0p[r] += __shfl_xor(T0p[r], off);
    }

  // atomic accumulation across slices (HW f32 atomics)
#pragma unroll
  for (int r = 0; r < 4; ++r) {
    int row = sBase + lg * 4 + r;
#pragma unroll
    for (int dj = 0; dj < 4; ++dj)
      unsafeAtomicAdd(&Tacc[row * 64 + dj * 16 + lm], accT[dj][r]);
    if (lm == 0) {
      unsafeAtomicAdd(&Lacc[row],  Lp[r]);
      unsafeAtomicAdd(&WCacc[row], WCp[r]);
      unsafeAtomicAdd(&T0acc[row], T0p[r]);
    }
  }
}

// ---------------------------------------------------------------------------
// Combine: one wave per (b,s) row. f32 fast math; f64 only for the <t,t>
// reduction feeding the tangency identity mk = <t,t> + wc^2.
// ---------------------------------------------------------------------------
__global__ __launch_bounds__(256) void combine_kernel(
    const float* __restrict__ Q0, const unsigned short* __restrict__ Qh,
    const unsigned short* __restrict__ Ql,
    const float* __restrict__ Tacc, const float* __restrict__ T0acc,
    const float* __restrict__ Lacc, const float* __restrict__ WCacc,
    float* __restrict__ out)
{
  int wid = (blockIdx.x << 2) + (threadIdx.x >> 6);
  int lane = threadIdx.x & 63;

  int qi = wid * 64 + lane;
  float Tsum = Tacc[qi];
  float T0 = T0acc[wid];
  float L  = Lacc[wid];
  float WC = WCacc[wid];

  float qd = bf16_tof(Qh[qi]) + bf16_tof(Ql[qi]);
  float q0 = Q0[wid];
  float invL = 1.0f / L;
  float td = Tsum * invL;
  float t0 = T0 * invL;
  float wc = WC * invL;

  double tt = (double)td * (double)td;
#pragma unroll
  for (int off = 1; off < 64; off <<= 1) tt += __shfl_xor(tt, off);
  tt -= (double)t0 * (double)t0;
  double mk = tt + (double)wc * (double)wc;

  float un = (float)sqrt(fmax(mk, 1e-12));
  float eu = __expf(un);
  float ru = 1.0f / eu;
  float ch = 0.5f * (eu + ru);
  float shu = 0.5f * (eu - ru) / un;

  float tmd = td + wc * qd;
  float tm0 = t0 + wc * q0;
  float zd = ch * qd + shu * tmd;
  float z0 = ch * q0 + shu * tm0;

  float p2 = zd * zd;
#pragma unroll
  for (int off = 1; off < 64; off <<= 1) p2 += __shfl_xor(p2, off);
  float yn = fmaxf(sqrtf(p2), EPSF);
  float zc = fmaxf(z0, 1.0f + EPSF);
  float dl = __logf(zc + sqrtf(fmaxf(zc * zc - 1.0f, 0.f)));
  out[qi] = dl * zd / yn;
}

// ---------------------------------------------------------------------------
extern "C" void kernel_launch(void* const* d_in, const int* in_sizes, int n_in,
                              void* d_out, int out_size, void* d_ws, size_t ws_size,
                              hipStream_t stream)
{
  const float* queries = (const float*)d_in[0];
  const float* keys    = (const float*)d_in[1];
  const float* values  = (const float*)d_in[2];
  const float* Wq      = (const float*)d_in[3];
  const float* bq      = (const float*)d_in[4];
  const float* Wk      = (const float*)d_in[5];
  const float* bk      = (const float*)d_in[6];
  const float* Wv      = (const float*)d_in[7];
  const float* bv      = (const float*)d_in[8];
  float* out = (float*)d_out;
  float* ws  = (float*)d_ws;

  float* Q0 = ws;                                   // 4096
  float* K0 = ws + 4096;                            // 8192
  float* V0 = ws + 12288;                           // 8192
  unsigned short* Qh  = (unsigned short*)(ws + 20480);
  unsigned short* Ql  = (unsigned short*)(ws + 151552);
  unsigned short* Kh  = (unsigned short*)(ws + 282624);
  unsigned short* Kl  = (unsigned short*)(ws + 544768);
  unsigned short* Vh  = (unsigned short*)(ws + 806912);
  unsigned short* Vl  = (unsigned short*)(ws + 1069056);
  unsigned short* Vth = (unsigned short*)(ws + 1331200);  // [64][8192]
  unsigned short* Vtl = (unsigned short*)(ws + 1593344);
  float* Tacc  = ws + 1855488;                      // 4096*64 = 262144
  float* T0acc = ws + 2117632;                      // 4096
  float* Lacc  = ws + 2121728;                      // 4096
  float* WCacc = ws + 2125824;                      // 4096
  // zero region: Tacc..WCacc = 274432 floats = ZERO_F4*4

  proj_kernel<<<320, 256, 0, stream>>>(queries, keys, values, Wq, bq, Wk, bk,
                                       Wv, bv, Q0, K0, V0, Qh, Ql, Kh, Kl,
                                       Vh, Vl, Vth, Vtl, Tacc);
  attn_kernel<<<1024, 256, 0, stream>>>(
      Q0, Qh, Ql, K0, Kh, Kl, V0, Vh, Vl, Vth, Vtl,
      Tacc, T0acc, Lacc, WCacc);
  combine_kernel<<<1024, 256, 0, stream>>>(
      Q0, Qh, Ql, Tacc, T0acc, Lacc, WCacc, out);
}

// Round 10
// 157.080 us; speedup vs baseline: 1.3139x; 1.3139x over previous
//
#include <hip/hip_runtime.h>
#include <math.h>

#define BETA  0.125f    // 1/sqrt(64)
#define SHIFT 30.0f     // fixed softmax shift; logits bounded in [0.125, 68.5]
#define EPSF  1e-7f

typedef __attribute__((ext_vector_type(8))) short short8;
typedef __attribute__((ext_vector_type(4))) short short4v;
typedef __attribute__((ext_vector_type(4))) float f32x4;

__device__ __forceinline__ unsigned short bf16_rne(float x) {
  unsigned int u = __float_as_uint(x);
  return (unsigned short)((u + 0x7fffu + ((u >> 16) & 1u)) >> 16);
}
__device__ __forceinline__ float bf16_tof(unsigned short h) {
  return __uint_as_float(((unsigned int)h) << 16);
}
__device__ __forceinline__ void split2(float x, unsigned short& h, unsigned short& l) {
  unsigned int u = __float_as_uint(x);
  unsigned int hr = (u + 0x7fffu + ((u >> 16) & 1u)) & 0xffff0000u;  // RNE hi
  h = (unsigned short)(hr >> 16);
  l = bf16_rne(x - __uint_as_float(hr));
}

#define ZERO_F4 68608   // (262144 + 12288) floats / 4: Tacc + scalar accums

// ---------------------------------------------------------------------------
// Merged projection (r9-proven). Blocks 0..127: V (heavy, first); 128..255: K;
// 256..319: Q. Also zeroes the attention accumulator region.
// ---------------------------------------------------------------------------
__global__ __launch_bounds__(256) void proj_kernel(
    const float* __restrict__ Xq, const float* __restrict__ Xk,
    const float* __restrict__ Xv,
    const float* __restrict__ Wq, const float* __restrict__ bq,
    const float* __restrict__ Wk, const float* __restrict__ bk,
    const float* __restrict__ Wv, const float* __restrict__ bv,
    float* __restrict__ Q0, float* __restrict__ K0, float* __restrict__ V0,
    unsigned short* __restrict__ Qh, unsigned short* __restrict__ Ql,
    unsigned short* __restrict__ Kh, unsigned short* __restrict__ Kl,
    unsigned short* __restrict__ Vh, unsigned short* __restrict__ Vl,
    unsigned short* __restrict__ Vth, unsigned short* __restrict__ Vtl,
    float* __restrict__ zeroRegion)
{
  __shared__ float Xs[64 * 64];
  __shared__ float Ws[64 * 64];
  __shared__ unsigned int Tr[64 * 65];   // dedicated transpose buffer (V only)

  const int bid = blockIdx.x;
  const int tid = threadIdx.x;

  {
    int idx = bid * 256 + tid;
    if (idx < ZERO_F4)
      *(float4*)&zeroRegion[idx * 4] = make_float4(0.f, 0.f, 0.f, 0.f);
  }

  const float *X, *W, *bias;
  float* y0;
  unsigned short *yh, *yl;
  bool dbl;
  int rowBase;
  if (bid < 128)      { X = Xv; W = Wk; bias = bk; y0 = V0; yh = Vh; yl = Vl; rowBase = bid << 6;         dbl = true;  }
  else if (bid < 256) { X = Xk; W = Wk; bias = bk; y0 = K0; yh = Kh; yl = Kl; rowBase = (bid - 128) << 6; dbl = false; }
  else                { X = Xq; W = Wq; bias = bq; y0 = Q0; yh = Qh; yl = Ql; rowBase = (bid - 256) << 6; dbl = false; }

  const int ty = tid >> 4, tx = tid & 15;
  const int ty4 = ty << 2, tx4 = tx << 2;

  float acc[4][4];
#pragma unroll
  for (int j = 0; j < 4; ++j) {
    float bj = bias[tx4 + j];
#pragma unroll
    for (int i = 0; i < 4; ++i) acc[i][j] = bj;
  }

  for (int kc = 0; kc < 4; ++kc) {
#pragma unroll
    for (int q = 0; q < 4; ++q) {
      int f = tid + (q << 8);
      int r = f >> 4, g = f & 15;
      int sw = (r << 6) + ((g ^ (r >> 2)) << 2);
      *(float4*)&Xs[sw] = *(const float4*)&X[(rowBase + r) * 256 + (kc << 6) + (g << 2)];
      *(float4*)&Ws[sw] = *(const float4*)&W[r * 256 + (kc << 6) + (g << 2)];
    }
    __syncthreads();
#pragma unroll 4
    for (int kk = 0; kk < 64; kk += 4) {
      const int gk = kk >> 2;
      float4 xa[4], wb[4];
#pragma unroll
      for (int i = 0; i < 4; ++i)
        xa[i] = *(const float4*)&Xs[((ty4 + i) << 6) + ((gk ^ ty) << 2)];
#pragma unroll
      for (int j = 0; j < 4; ++j)
        wb[j] = *(const float4*)&Ws[((tx4 + j) << 6) + ((gk ^ tx) << 2)];
#pragma unroll
      for (int i = 0; i < 4; ++i)
#pragma unroll
        for (int j = 0; j < 4; ++j)
          acc[i][j] += xa[i].x * wb[j].x + xa[i].y * wb[j].y +
                       xa[i].z * wb[j].z + xa[i].w * wb[j].w;
    }
    __syncthreads();
  }

  if (dbl) {
#pragma unroll
    for (int i = 0; i < 4; ++i) {
      float4 v = make_float4(acc[i][0], acc[i][1], acc[i][2], acc[i][3]);
      *(float4*)&Xs[((ty4 + i) << 6) + ((tx ^ ty) << 2)] = v;
    }
#pragma unroll
    for (int q = 0; q < 4; ++q) {
      int f = tid + (q << 8);
      int r = f >> 4, g = f & 15;
      int sw = (r << 6) + ((g ^ (r >> 2)) << 2);
      *(float4*)&Ws[sw] = *(const float4*)&Wv[(r << 6) + (g << 2)];
    }
#pragma unroll
    for (int j = 0; j < 4; ++j) {
      float bj = bv[tx4 + j];
#pragma unroll
      for (int i = 0; i < 4; ++i) acc[i][j] = bj;
    }
    __syncthreads();
#pragma unroll 4
    for (int kk = 0; kk < 64; kk += 4) {
      const int gk = kk >> 2;
      float4 xa[4], wb[4];
#pragma unroll
      for (int i = 0; i < 4; ++i)
        xa[i] = *(const float4*)&Xs[((ty4 + i) << 6) + ((gk ^ ty) << 2)];
#pragma unroll
      for (int j = 0; j < 4; ++j)
        wb[j] = *(const float4*)&Ws[((tx4 + j) << 6) + ((gk ^ tx) << 2)];
#pragma unroll
      for (int i = 0; i < 4; ++i)
#pragma unroll
        for (int j = 0; j < 4; ++j)
          acc[i][j] += xa[i].x * wb[j].x + xa[i].y * wb[j].y +
                       xa[i].z * wb[j].z + xa[i].w * wb[j].w;
    }
  }

  // expmap0 epilogue in registers + shuffles
  float n2p[4];
#pragma unroll
  for (int i = 0; i < 4; ++i)
    n2p[i] = acc[i][0] * acc[i][0] + acc[i][1] * acc[i][1] +
             acc[i][2] * acc[i][2] + acc[i][3] * acc[i][3];
#pragma unroll
  for (int i = 0; i < 4; ++i) {
    n2p[i] += __shfl_xor(n2p[i], 1);
    n2p[i] += __shfl_xor(n2p[i], 2);
    n2p[i] += __shfl_xor(n2p[i], 4);
    n2p[i] += __shfl_xor(n2p[i], 8);
  }
  unsigned short hv[4][4], lv[4][4];
#pragma unroll
  for (int i = 0; i < 4; ++i) {
    float n = sqrtf(n2p[i]);
    float factor = fminf(3.5f / (n + EPSF), 1.0f);
    float xn = fmaxf(n * factor, EPSF);
    float et = __expf(xn);
    float rt = __builtin_amdgcn_rcpf(et);
    float ch = 0.5f * (et + rt);
    float sh = 0.5f * (et - rt);
    float scale = sh * factor * __builtin_amdgcn_rcpf(xn);
    int row = rowBase + ty4 + i;
    if (tx == 0) y0[row] = ch;
#pragma unroll
    for (int j = 0; j < 4; ++j) split2(acc[i][j] * scale, hv[i][j], lv[i][j]);
    unsigned int* ph = (unsigned int*)(yh + row * 64 + tx4);
    ph[0] = (unsigned int)hv[i][0] | ((unsigned int)hv[i][1] << 16);
    ph[1] = (unsigned int)hv[i][2] | ((unsigned int)hv[i][3] << 16);
    unsigned int* pl = (unsigned int*)(yl + row * 64 + tx4);
    pl[0] = (unsigned int)lv[i][0] | ((unsigned int)lv[i][1] << 16);
    pl[1] = (unsigned int)lv[i][2] | ((unsigned int)lv[i][3] << 16);
  }

  if (dbl) {
    // transposed copies via dedicated LDS buffer; two passes (hi, lo)
#pragma unroll
    for (int i = 0; i < 4; ++i)
#pragma unroll
      for (int j = 0; j < 4; ++j)
        Tr[(ty4 + i) * 65 + tx4 + j] = (unsigned int)hv[i][j];
    __syncthreads();
#pragma unroll
    for (int q = 0; q < 2; ++q) {
      int f = tid + (q << 8);
      int d = f >> 3;
      int seg = (f & 7) << 3;
      unsigned int o[4];
#pragma unroll
      for (int k = 0; k < 4; ++k)
        o[k] = Tr[(seg + 2 * k) * 65 + d] | (Tr[(seg + 2 * k + 1) * 65 + d] << 16);
      *(uint4*)&Vth[d * 8192 + rowBase + seg] = make_uint4(o[0], o[1], o[2], o[3]);
    }
    __syncthreads();
#pragma unroll
    for (int i = 0; i < 4; ++i)
#pragma unroll
      for (int j = 0; j < 4; ++j)
        Tr[(ty4 + i) * 65 + tx4 + j] = (unsigned int)lv[i][j];
    __syncthreads();
#pragma unroll
    for (int q = 0; q < 2; ++q) {
      int f = tid + (q << 8);
      int d = f >> 3;
      int seg = (f & 7) << 3;
      unsigned int o[4];
#pragma unroll
      for (int k = 0; k < 4; ++k)
        o[k] = Tr[(seg + 2 * k) * 65 + d] | (Tr[(seg + 2 * k + 1) * 65 + d] << 16);
      *(uint4*)&Vtl[d * 8192 + rowBase + seg] = make_uint4(o[0], o[1], o[2], o[3]);
    }
  }
}

// ---------------------------------------------------------------------------
// MFMA attention core, WG-cooperative LDS staging. WG = 4 waves x 32 s-rows
// = 128 s-rows, one m-slice of 256 (4 chunks of 64). Per chunk: stage
// Kh/Kl/Vh/Vl + transposed Vth/Vtl tiles (6 x 64x72 u16) into LDS, then both
// MFMA phases read LDS only. W tile (bf16) overlays the consumed K region
// after a barrier. Atomic f32 accumulation across slices (Tacc zeroed by proj).
// ---------------------------------------------------------------------------
__global__ void __attribute__((amdgpu_waves_per_eu(2, 2)))
__launch_bounds__(256) attn_kernel(
    const float* __restrict__ Q0g, const unsigned short* __restrict__ Qh,
    const unsigned short* __restrict__ Ql,
    const float* __restrict__ K0g, const unsigned short* __restrict__ Khg,
    const unsigned short* __restrict__ Klg,
    const float* __restrict__ V0g, const unsigned short* __restrict__ Vhg,
    const unsigned short* __restrict__ Vlg,
    const unsigned short* __restrict__ Vthg, const unsigned short* __restrict__ Vtlg,
    float* __restrict__ Tacc, float* __restrict__ T0acc,
    float* __restrict__ Lacc, float* __restrict__ WCacc)
{
  // 6 tiles of 64 rows x 72 u16 (stride 72 => every b128 16B-aligned):
  // 0:Kh 1:Kl 2:Vh 3:Vl 4:Vth 5:Vtl. W (bf16, 4 waves x 32x68) overlays 0-1.
  __shared__ unsigned short LB[6 * 4608];

  const int tid = threadIdx.x;
  const int wave = tid >> 6, lane = tid & 63;
  const int lm = lane & 15;
  const int lg = lane >> 4;
  const int bid = blockIdx.x;          // 512 blocks
  const int slice = bid & 15;          // SL = 16
  const int t = bid >> 4;              // 0..31
  const int b = t >> 4;
  const int sT = t & 15;
  const int sBase = b * 2048 + sT * 128 + wave * 32;

  unsigned short* wbase = LB + wave * 2176;  // 32*68 u16, overlays K region

  // loop-invariant Q fragments [si][kstep][hi/lo]
  short8 qf[2][2][2];
#pragma unroll
  for (int si = 0; si < 2; ++si)
#pragma unroll
    for (int ks = 0; ks < 2; ++ks) {
      int idx = (sBase + si * 16 + lm) * 64 + ks * 32 + lg * 8;
      qf[si][ks][0] = *(const short8*)(Qh + idx);
      qf[si][ks][1] = *(const short8*)(Ql + idx);
    }
  float q0r[2][4];
#pragma unroll
  for (int si = 0; si < 2; ++si)
#pragma unroll
    for (int r = 0; r < 4; ++r)
      q0r[si][r] = Q0g[sBase + si * 16 + lg * 4 + r];

  f32x4 accT[2][4];
  float Lp[2][4], WCp[2][4], T0p[2][4];
#pragma unroll
  for (int si = 0; si < 2; ++si)
#pragma unroll
    for (int r = 0; r < 4; ++r) {
      Lp[si][r] = 0.f; WCp[si][r] = 0.f; T0p[si][r] = 0.f;
    }
#pragma unroll
  for (int si = 0; si < 2; ++si)
#pragma unroll
    for (int dj = 0; dj < 4; ++dj) accT[si][dj] = f32x4{0.f, 0.f, 0.f, 0.f};

  const int mSliceBase = b * 4096 + slice * 256;   // 4 chunks of 64
  const int frow = tid >> 3;            // 0..31 per q-pass
  const int fc8 = (tid & 7) << 3;       // 0,8,..,56
  for (int mc = 0; mc < 4; ++mc) {
    const int mCh = mSliceBase + (mc << 6);

    // ---- stage 6 tiles: rows 0..63, 16B per (thread, pass) per tile ----
#pragma unroll
    for (int q = 0; q < 2; ++q) {
      int row = frow + (q << 5);
      int goff = (mCh + row) * 64 + fc8;
      int loff = row * 72 + fc8;
      *(uint4*)&LB[loff]            = *(const uint4*)&Khg[goff];
      *(uint4*)&LB[4608 + loff]     = *(const uint4*)&Klg[goff];
      *(uint4*)&LB[2 * 4608 + loff] = *(const uint4*)&Vhg[goff];
      *(uint4*)&LB[3 * 4608 + loff] = *(const uint4*)&Vlg[goff];
      int gofft = row * 8192 + mCh + fc8;            // row = d for Vt tiles
      *(uint4*)&LB[4 * 4608 + loff] = *(const uint4*)&Vthg[gofft];
      *(uint4*)&LB[5 * 4608 + loff] = *(const uint4*)&Vtlg[gofft];
    }
    float k0r[4], v0r[4];
#pragma unroll
    for (int mj = 0; mj < 4; ++mj) {
      k0r[mj] = K0g[mCh + mj * 16 + lm];
      v0r[mj] = V0g[mCh + mj * 16 + lm];
    }
    __syncthreads();

    // ---- Phase A: sims = Qr.Kr, ipv = Qr.Vr (LDS B-frags) ----
    f32x4 sims[2][4], ipv[2][4];
#pragma unroll
    for (int si = 0; si < 2; ++si)
#pragma unroll
      for (int mj = 0; mj < 4; ++mj) {
        sims[si][mj] = f32x4{0.f, 0.f, 0.f, 0.f};
        ipv[si][mj]  = f32x4{0.f, 0.f, 0.f, 0.f};
      }
#pragma unroll
    for (int mj = 0; mj < 4; ++mj) {
#pragma unroll
      for (int ks = 0; ks < 2; ++ks) {
        int off = (mj * 16 + lm) * 72 + ks * 32 + lg * 8;
        short8 kh = *(const short8*)&LB[off];
        short8 kl = *(const short8*)&LB[4608 + off];
        short8 vh = *(const short8*)&LB[2 * 4608 + off];
        short8 vl = *(const short8*)&LB[3 * 4608 + off];
#pragma unroll
        for (int si = 0; si < 2; ++si) {
          sims[si][mj] = __builtin_amdgcn_mfma_f32_16x16x32_bf16(qf[si][ks][0], kh, sims[si][mj], 0, 0, 0);
          sims[si][mj] = __builtin_amdgcn_mfma_f32_16x16x32_bf16(qf[si][ks][0], kl, sims[si][mj], 0, 0, 0);
          sims[si][mj] = __builtin_amdgcn_mfma_f32_16x16x32_bf16(qf[si][ks][1], kh, sims[si][mj], 0, 0, 0);
          ipv[si][mj]  = __builtin_amdgcn_mfma_f32_16x16x32_bf16(qf[si][ks][0], vh, ipv[si][mj], 0, 0, 0);
          ipv[si][mj]  = __builtin_amdgcn_mfma_f32_16x16x32_bf16(qf[si][ks][0], vl, ipv[si][mj], 0, 0, 0);
          ipv[si][mj]  = __builtin_amdgcn_mfma_f32_16x16x32_bf16(qf[si][ks][1], vh, ipv[si][mj], 0, 0, 0);
        }
      }
    }
    __syncthreads();  // all waves done reading K tiles; W may overlay

    // ---- elementwise: w = e * acosh(-c) * rsq(c^2-1); W -> LDS (bf16) ----
#pragma unroll
    for (int si = 0; si < 2; ++si)
#pragma unroll
      for (int mj = 0; mj < 4; ++mj)
#pragma unroll
        for (int r = 0; r < 4; ++r) {
          float c  = ipv[si][mj][r]  - q0r[si][r] * v0r[mj];
          float sm = sims[si][mj][r] - q0r[si][r] * k0r[mj];
          float x = -c;
          float s2 = fmaxf(fmaf(x, x, -1.0f), EPSF);
          float rs = __builtin_amdgcn_rsqf(s2);
          float dist = __logf(fmaf(s2, rs, x));
          float e = __expf(fmaf(-BETA, sm, -SHIFT));
          float w = e * dist * rs;
          unsigned short wu = bf16_rne(w);
          float wb = bf16_tof(wu);
          Lp[si][r]  += e;
          WCp[si][r] += wb * c;
          T0p[si][r] += wb * v0r[mj];
          wbase[(si * 16 + lg * 4 + r) * 68 + mj * 16 + lm] = wu;
        }

    // ---- Phase B: T[s][d] += W[s][m] * V[m][d] (A=W LDS, B=Vt LDS) ----
#pragma unroll
    for (int ks = 0; ks < 2; ++ks) {
      short8 wa[2];
#pragma unroll
      for (int si = 0; si < 2; ++si) {
        const unsigned short* p = wbase + (si * 16 + lm) * 68 + ks * 32 + lg * 8;
        short4v a0 = *(const short4v*)p;
        short4v a1 = *(const short4v*)(p + 4);
        wa[si] = __builtin_shufflevector(a0, a1, 0, 1, 2, 3, 4, 5, 6, 7);
      }
#pragma unroll
      for (int dj = 0; dj < 4; ++dj) {
        int off = (dj * 16 + lm) * 72 + ks * 32 + lg * 8;
        short8 th = *(const short8*)&LB[4 * 4608 + off];
        short8 tl = *(const short8*)&LB[5 * 4608 + off];
#pragma unroll
        for (int si = 0; si < 2; ++si) {
          accT[si][dj] = __builtin_amdgcn_mfma_f32_16x16x32_bf16(wa[si], th, accT[si][dj], 0, 0, 0);
          accT[si][dj] = __builtin_amdgcn_mfma_f32_16x16x32_bf16(wa[si], tl, accT[si][dj], 0, 0, 0);
        }
      }
    }
    __syncthreads();  // Vt/W consumed before next chunk's staging
  }

  // reduce row scalars across the 16 col-lanes
#pragma unroll
  for (int si = 0; si < 2; ++si)
#pragma unroll
    for (int r = 0; r < 4; ++r)
#pragma unroll
      for (int off = 1; off < 16; off <<= 1) {
        Lp[si][r]  += __shfl_xor(Lp[si][r], off);
        WCp[si][r] += __shfl_xor(WCp[si][r], off);
        T0p[si][r] += __shfl_xor(T0p[si][r], off);
      }

  // atomic accumulation across slices (HW f32 atomics)
#pragma unroll
  for (int si = 0; si < 2; ++si)
#pragma unroll
    for (int r = 0; r < 4; ++r) {
      int row = sBase + si * 16 + lg * 4 + r;
#pragma unroll
      for (int dj = 0; dj < 4; ++dj)
        unsafeAtomicAdd(&Tacc[row * 64 + dj * 16 + lm], accT[si][dj][r]);
      if (lm == 0) {
        unsafeAtomicAdd(&Lacc[row],  Lp[si][r]);
        unsafeAtomicAdd(&WCacc[row], WCp[si][r]);
        unsafeAtomicAdd(&T0acc[row], T0p[si][r]);
      }
    }
}

// ---------------------------------------------------------------------------
// Combine (r9-proven): one wave per (b,s) row. f32 fast math; f64 only for
// the <t,t> reduction feeding the tangency identity mk = <t,t> + wc^2.
// ---------------------------------------------------------------------------
__global__ __launch_bounds__(256) void combine_kernel(
    const float* __restrict__ Q0, const unsigned short* __restrict__ Qh,
    const unsigned short* __restrict__ Ql,
    const float* __restrict__ Tacc, const float* __restrict__ T0acc,
    const float* __restrict__ Lacc, const float* __restrict__ WCacc,
    float* __restrict__ out)
{
  int wid = (blockIdx.x << 2) + (threadIdx.x >> 6);
  int lane = threadIdx.x & 63;

  int qi = wid * 64 + lane;
  float Tsum = Tacc[qi];
  float T0 = T0acc[wid];
  float L  = Lacc[wid];
  float WC = WCacc[wid];

  float qd = bf16_tof(Qh[qi]) + bf16_tof(Ql[qi]);
  float q0 = Q0[wid];
  float invL = 1.0f / L;
  float td = Tsum * invL;
  float t0 = T0 * invL;
  float wc = WC * invL;

  double tt = (double)td * (double)td;
#pragma unroll
  for (int off = 1; off < 64; off <<= 1) tt += __shfl_xor(tt, off);
  tt -= (double)t0 * (double)t0;
  double mk = tt + (double)wc * (double)wc;

  float un = (float)sqrt(fmax(mk, 1e-12));
  float eu = __expf(un);
  float ru = 1.0f / eu;
  float ch = 0.5f * (eu + ru);
  float shu = 0.5f * (eu - ru) / un;

  float tmd = td + wc * qd;
  float tm0 = t0 + wc * q0;
  float zd = ch * qd + shu * tmd;
  float z0 = ch * q0 + shu * tm0;

  float p2 = zd * zd;
#pragma unroll
  for (int off = 1; off < 64; off <<= 1) p2 += __shfl_xor(p2, off);
  float yn = fmaxf(sqrtf(p2), EPSF);
  float zc = fmaxf(z0, 1.0f + EPSF);
  float dl = __logf(zc + sqrtf(fmaxf(zc * zc - 1.0f, 0.f)));
  out[qi] = dl * zd / yn;
}

// ---------------------------------------------------------------------------
extern "C" void kernel_launch(void* const* d_in, const int* in_sizes, int n_in,
                              void* d_out, int out_size, void* d_ws, size_t ws_size,
                              hipStream_t stream)
{
  const float* queries = (const float*)d_in[0];
  const float* keys    = (const float*)d_in[1];
  const float* values  = (const float*)d_in[2];
  const float* Wq      = (const float*)d_in[3];
  const float* bq      = (const float*)d_in[4];
  const float* Wk      = (const float*)d_in[5];
  const float* bk      = (const float*)d_in[6];
  const float* Wv      = (const float*)d_in[7];
  const float* bv      = (const float*)d_in[8];
  float* out = (float*)d_out;
  float* ws  = (float*)d_ws;

  float* Q0 = ws;                                   // 4096
  float* K0 = ws + 4096;                            // 8192
  float* V0 = ws + 12288;                           // 8192
  unsigned short* Qh  = (unsigned short*)(ws + 20480);
  unsigned short* Ql  = (unsigned short*)(ws + 151552);
  unsigned short* Kh  = (unsigned short*)(ws + 282624);
  unsigned short* Kl  = (unsigned short*)(ws + 544768);
  unsigned short* Vh  = (unsigned short*)(ws + 806912);
  unsigned short* Vl  = (unsigned short*)(ws + 1069056);
  unsigned short* Vth = (unsigned short*)(ws + 1331200);  // [64][8192]
  unsigned short* Vtl = (unsigned short*)(ws + 1593344);
  float* Tacc  = ws + 1855488;                      // 4096*64 = 262144
  float* T0acc = ws + 2117632;                      // 4096
  float* Lacc  = ws + 2121728;                      // 4096
  float* WCacc = ws + 2125824;                      // 4096

  proj_kernel<<<320, 256, 0, stream>>>(queries, keys, values, Wq, bq, Wk, bk,
                                       Wv, bv, Q0, K0, V0, Qh, Ql, Kh, Kl,
                                       Vh, Vl, Vth, Vtl, Tacc);
  attn_kernel<<<512, 256, 0, stream>>>(
      Q0, Qh, Ql, K0, Kh, Kl, V0, Vh, Vl, Vth, Vtl,
      Tacc, T0acc, Lacc, WCacc);
  combine_kernel<<<1024, 256, 0, stream>>>(
      Q0, Qh, Ql, Tacc, T0acc, Lacc, WCacc, out);
}